// Round 1
// baseline (607.437 us; speedup 1.0000x reference)
//
#include <hip/hip_runtime.h>

#define N_NODES 20000
#define N_EDGES 320000
#define N_GRAPHS 128
#define IN_DIM 128
#define HDIM 256
#define LAYERS 4
#define EPSV 1e-5f

// ---------------- CSR build ----------------
__global__ void k_zero_cnt(int* cnt) {
    int i = blockIdx.x * 256 + threadIdx.x;
    if (i < N_NODES) cnt[i] = 0;
}

__global__ void k_count(const int* __restrict__ dst, int* __restrict__ cnt) {
    int e = blockIdx.x * 256 + threadIdx.x;
    if (e < N_EDGES) atomicAdd(&cnt[dst[e]], 1);
}

__global__ void k_dinv(const int* __restrict__ cnt, float* __restrict__ dinv) {
    int i = blockIdx.x * 256 + threadIdx.x;
    if (i < N_NODES) dinv[i] = rsqrtf((float)cnt[i] + 1.0f);  // +1 self loop
}

// single-block scan: rp[0]=0, rp[i+1]=rp[i]+cnt[i]
__global__ void k_scan(const int* __restrict__ cnt, int* __restrict__ rp) {
    __shared__ int wsum[16];
    __shared__ int woff[17];
    int tid = threadIdx.x, lane = tid & 63, w = tid >> 6;
    int running = 0;
    if (tid == 0) rp[0] = 0;
    for (int base = 0; base < N_NODES; base += 1024) {
        int i = base + tid;
        int v = (i < N_NODES) ? cnt[i] : 0;
        int x = v;
        #pragma unroll
        for (int d = 1; d < 64; d <<= 1) {
            int t = __shfl_up(x, d, 64);
            if (lane >= d) x += t;
        }
        if (lane == 63) wsum[w] = x;
        __syncthreads();
        if (tid == 0) {
            int acc = 0;
            for (int k = 0; k < 16; k++) { woff[k] = acc; acc += wsum[k]; }
            woff[16] = acc;
        }
        __syncthreads();
        int incl = x + woff[w] + running;
        if (i < N_NODES) rp[i + 1] = incl;
        running += woff[16];
        __syncthreads();
    }
}

__global__ void k_cursor(const int* __restrict__ rp, int* __restrict__ cursor) {
    int i = blockIdx.x * 256 + threadIdx.x;
    if (i < N_NODES) cursor[i] = rp[i];
}

__global__ void k_scatter(const int* __restrict__ src, const int* __restrict__ dst,
                          int* __restrict__ cursor, int* __restrict__ col) {
    int e = blockIdx.x * 256 + threadIdx.x;
    if (e < N_EDGES) {
        int d = dst[e];
        int p = atomicAdd(&cursor[d], 1);
        col[p] = src[e];
    }
}

// ---------------- GEMM: C[M x 256] = A[M x K] @ B[K x 256] (+bias) ----------------
template <int K>
__global__ __launch_bounds__(256) void k_gemm(const float* __restrict__ A,
                                              const float* __restrict__ B,
                                              const float* __restrict__ bias,
                                              float* __restrict__ C, int M) {
    __shared__ float As[16][65];
    __shared__ float Bs[16][64];
    const int tid = threadIdx.x;
    const int tx = tid & 15, ty = tid >> 4;
    const int m0 = blockIdx.x * 64, n0 = blockIdx.y * 64;
    const int lmi = tid >> 2, lk4 = (tid & 3) * 4;   // A loader: row lmi, k quad
    const int lbk = tid >> 4, lbn = (tid & 15) * 4;  // B loader: k row, col quad

    float acc[4][4] = {};

    for (int k0 = 0; k0 < K; k0 += 16) {
        __syncthreads();
        float4 av = make_float4(0.f, 0.f, 0.f, 0.f);
        int ar = m0 + lmi;
        if (ar < M) av = *reinterpret_cast<const float4*>(A + (size_t)ar * K + k0 + lk4);
        As[lk4 + 0][lmi] = av.x;
        As[lk4 + 1][lmi] = av.y;
        As[lk4 + 2][lmi] = av.z;
        As[lk4 + 3][lmi] = av.w;
        float4 bv = *reinterpret_cast<const float4*>(B + (size_t)(k0 + lbk) * HDIM + n0 + lbn);
        *reinterpret_cast<float4*>(&Bs[lbk][lbn]) = bv;
        __syncthreads();
        #pragma unroll
        for (int k = 0; k < 16; k++) {
            float a0 = As[k][ty * 4 + 0], a1 = As[k][ty * 4 + 1];
            float a2 = As[k][ty * 4 + 2], a3 = As[k][ty * 4 + 3];
            float b0 = Bs[k][tx * 4 + 0], b1 = Bs[k][tx * 4 + 1];
            float b2 = Bs[k][tx * 4 + 2], b3 = Bs[k][tx * 4 + 3];
            acc[0][0] += a0 * b0; acc[0][1] += a0 * b1; acc[0][2] += a0 * b2; acc[0][3] += a0 * b3;
            acc[1][0] += a1 * b0; acc[1][1] += a1 * b1; acc[1][2] += a1 * b2; acc[1][3] += a1 * b3;
            acc[2][0] += a2 * b0; acc[2][1] += a2 * b1; acc[2][2] += a2 * b2; acc[2][3] += a2 * b3;
            acc[3][0] += a3 * b0; acc[3][1] += a3 * b1; acc[3][2] += a3 * b2; acc[3][3] += a3 * b3;
        }
    }

    #pragma unroll
    for (int i = 0; i < 4; i++) {
        int r = m0 + ty * 4 + i;
        if (r >= M) continue;
        int c = n0 + tx * 4;
        float4 v;
        v.x = acc[i][0]; v.y = acc[i][1]; v.z = acc[i][2]; v.w = acc[i][3];
        if (bias) {
            v.x += bias[c + 0]; v.y += bias[c + 1]; v.z += bias[c + 2]; v.w += bias[c + 3];
        }
        *reinterpret_cast<float4*>(C + (size_t)r * HDIM + c) = v;
    }
}

// ---------------- aggregate + bias + relu + bn + residual ----------------
__global__ __launch_bounds__(256) void k_aggregate(
    const float* __restrict__ m, const float* __restrict__ dinv,
    const int* __restrict__ rp, const int* __restrict__ col,
    const float* __restrict__ cb, const float* __restrict__ gamma,
    const float* __restrict__ beta, const float* __restrict__ mean,
    const float* __restrict__ var, float* __restrict__ h) {
    int i = blockIdx.x;
    int c = threadIdx.x;
    float di = dinv[i];
    float acc = di * m[(size_t)i * HDIM + c];  // self-loop (x di again below)
    int b = rp[i], e = rp[i + 1];
    for (int t = b; t < e; t++) {
        int s = col[t];
        acc += dinv[s] * m[(size_t)s * HDIM + c];
    }
    acc *= di;
    float v = acc + cb[c];
    v = fmaxf(v, 0.f);
    v = (v - mean[c]) * rsqrtf(var[c] + EPSV) * gamma[c] + beta[c];
    h[(size_t)i * HDIM + c] += v;
}

// ---------------- pooling (per-graph segment via binary search) ----------------
__device__ __forceinline__ int lower_bound_dev(const int* a, int n, int key) {
    int lo = 0, hi = n;
    while (lo < hi) {
        int mid = (lo + hi) >> 1;
        if (a[mid] < key) lo = mid + 1; else hi = mid;
    }
    return lo;
}

__global__ __launch_bounds__(256) void k_pool(const float* __restrict__ h,
                                              const int* __restrict__ batch,
                                              float* __restrict__ gbuf) {
    int g = blockIdx.x;
    int t = threadIdx.x;
    int start = lower_bound_dev(batch, N_NODES, g);
    int end = lower_bound_dev(batch, N_NODES, g + 1);
    float acc = 0.f;
    for (int n = start; n < end; n++) acc += h[(size_t)n * HDIM + t];
    int cnt = end - start;
    float mean = acc / fmaxf((float)cnt, 1.0f);
    gbuf[(size_t)g * 512 + t] = mean;
    gbuf[(size_t)g * 512 + 256 + t] = acc;
}

// ---------------- head: relu(g@W1+b1)@W2 + b2 ----------------
__global__ __launch_bounds__(256) void k_head(const float* __restrict__ gbuf,
                                              const float* __restrict__ w1,
                                              const float* __restrict__ b1,
                                              const float* __restrict__ w2,
                                              const float* __restrict__ b2,
                                              float* __restrict__ out) {
    int g = blockIdx.x;
    int t = threadIdx.x;
    __shared__ float gs[512];
    __shared__ float red[256];
    gs[t] = gbuf[(size_t)g * 512 + t];
    gs[256 + t] = gbuf[(size_t)g * 512 + 256 + t];
    __syncthreads();
    float acc = b1[t];
    for (int k = 0; k < 512; k++) acc += gs[k] * w1[(size_t)k * HDIM + t];
    acc = fmaxf(acc, 0.f);
    red[t] = acc * w2[t];
    __syncthreads();
    for (int s = 128; s > 0; s >>= 1) {
        if (t < s) red[t] += red[t + s];
        __syncthreads();
    }
    if (t == 0) out[g] = red[0] + b2[0];
}

extern "C" void kernel_launch(void* const* d_in, const int* in_sizes, int n_in,
                              void* d_out, int out_size, void* d_ws, size_t ws_size,
                              hipStream_t stream) {
    const float* x      = (const float*)d_in[0];
    const int*   ei     = (const int*)d_in[1];
    const int*   srcIdx = ei;
    const int*   dstIdx = ei + N_EDGES;
    const int*   batch  = (const int*)d_in[2];
    const float* enc_w  = (const float*)d_in[3];
    const float* enc_b  = (const float*)d_in[4];
    const float* conv_w = (const float*)d_in[5];
    const float* conv_b = (const float*)d_in[6];
    const float* gamma  = (const float*)d_in[7];
    const float* beta   = (const float*)d_in[8];
    const float* bmean  = (const float*)d_in[9];
    const float* bvar   = (const float*)d_in[10];
    const float* w1     = (const float*)d_in[11];
    const float* b1     = (const float*)d_in[12];
    const float* w2     = (const float*)d_in[13];
    const float* b2     = (const float*)d_in[14];
    float* out = (float*)d_out;

    char* ws = (char*)d_ws;
    size_t off = 0;
    auto alloc = [&](size_t bytes) -> void* {
        void* p = ws + off;
        off = (off + bytes + 255) & ~(size_t)255;
        return p;
    };
    int*   cnt    = (int*)alloc((size_t)N_NODES * 4);        // later reused as cursor
    int*   rp     = (int*)alloc((size_t)(N_NODES + 1) * 4);
    int*   col    = (int*)alloc((size_t)N_EDGES * 4);
    float* dinv   = (float*)alloc((size_t)N_NODES * 4);
    float* h      = (float*)alloc((size_t)N_NODES * HDIM * 4);
    float* m      = (float*)alloc((size_t)N_NODES * HDIM * 4);
    float* gbuf   = (float*)alloc((size_t)N_GRAPHS * 512 * 4);

    const int nb_nodes = (N_NODES + 255) / 256;
    const int nb_edges = (N_EDGES + 255) / 256;

    // degree + CSR
    k_zero_cnt<<<nb_nodes, 256, 0, stream>>>(cnt);
    k_count<<<nb_edges, 256, 0, stream>>>(dstIdx, cnt);
    k_dinv<<<nb_nodes, 256, 0, stream>>>(cnt, dinv);
    k_scan<<<1, 1024, 0, stream>>>(cnt, rp);
    k_cursor<<<nb_nodes, 256, 0, stream>>>(rp, cnt);  // cnt becomes cursor
    k_scatter<<<nb_edges, 256, 0, stream>>>(srcIdx, dstIdx, cnt, col);

    // encoder
    dim3 ggrid((N_NODES + 63) / 64, HDIM / 64);
    k_gemm<IN_DIM><<<ggrid, 256, 0, stream>>>(x, enc_w, enc_b, h, N_NODES);

    // conv layers
    for (int l = 0; l < LAYERS; l++) {
        k_gemm<HDIM><<<ggrid, 256, 0, stream>>>(h, conv_w + (size_t)l * HDIM * HDIM,
                                                nullptr, m, N_NODES);
        k_aggregate<<<N_NODES, 256, 0, stream>>>(m, dinv, rp, col,
                                                 conv_b + (size_t)l * HDIM,
                                                 gamma + (size_t)l * HDIM,
                                                 beta + (size_t)l * HDIM,
                                                 bmean + (size_t)l * HDIM,
                                                 bvar + (size_t)l * HDIM, h);
    }

    // pooling + head
    k_pool<<<N_GRAPHS, 256, 0, stream>>>(h, batch, gbuf);
    k_head<<<N_GRAPHS, 256, 0, stream>>>(gbuf, w1, b1, w2, b2, out);
}

// Round 2
// 388.934 us; speedup vs baseline: 1.5618x; 1.5618x over previous
//
#include <hip/hip_runtime.h>

#define N_NODES 20000
#define N_EDGES 320000
#define N_GRAPHS 128
#define IN_DIM 128
#define HDIM 256
#define LAYERS 4
#define EPSV 1e-5f

typedef unsigned short u16;
typedef __attribute__((ext_vector_type(8))) __bf16 bf16x8;
typedef __attribute__((ext_vector_type(4))) float f32x4;

__device__ __forceinline__ u16 f2bf(float f) {
    unsigned int u = __float_as_uint(f);
    u += 0x7FFFu + ((u >> 16) & 1u);
    return (u16)(u >> 16);
}
__device__ __forceinline__ float bf2f(u16 s) {
    return __uint_as_float((unsigned int)s << 16);
}

// ---------------- CSR build ----------------
__global__ void k_zero_cnt(int* cnt) {
    int i = blockIdx.x * 256 + threadIdx.x;
    if (i < N_NODES) cnt[i] = 0;
}

__global__ void k_count(const int* __restrict__ dst, int* __restrict__ cnt) {
    int e = blockIdx.x * 256 + threadIdx.x;
    if (e < N_EDGES) atomicAdd(&cnt[dst[e]], 1);
}

__global__ void k_dinv(const int* __restrict__ cnt, float* __restrict__ dinv) {
    int i = blockIdx.x * 256 + threadIdx.x;
    if (i < N_NODES) dinv[i] = rsqrtf((float)cnt[i] + 1.0f);  // +1 self loop
}

__global__ void k_scan(const int* __restrict__ cnt, int* __restrict__ rp) {
    __shared__ int wsum[16];
    __shared__ int woff[17];
    int tid = threadIdx.x, lane = tid & 63, w = tid >> 6;
    int running = 0;
    if (tid == 0) rp[0] = 0;
    for (int base = 0; base < N_NODES; base += 1024) {
        int i = base + tid;
        int v = (i < N_NODES) ? cnt[i] : 0;
        int x = v;
        #pragma unroll
        for (int d = 1; d < 64; d <<= 1) {
            int t = __shfl_up(x, d, 64);
            if (lane >= d) x += t;
        }
        if (lane == 63) wsum[w] = x;
        __syncthreads();
        if (tid == 0) {
            int acc = 0;
            for (int k = 0; k < 16; k++) { woff[k] = acc; acc += wsum[k]; }
            woff[16] = acc;
        }
        __syncthreads();
        int incl = x + woff[w] + running;
        if (i < N_NODES) rp[i + 1] = incl;
        running += woff[16];
        __syncthreads();
    }
}

__global__ void k_cursor(const int* __restrict__ rp, int* __restrict__ cursor) {
    int i = blockIdx.x * 256 + threadIdx.x;
    if (i < N_NODES) cursor[i] = rp[i];
}

__global__ void k_scatter(const int* __restrict__ src, const int* __restrict__ dst,
                          int* __restrict__ cursor, int* __restrict__ col) {
    int e = blockIdx.x * 256 + threadIdx.x;
    if (e < N_EDGES) {
        int d = dst[e];
        int p = atomicAdd(&cursor[d], 1);
        col[p] = src[e];
    }
}

// ---------------- fp32 -> bf16 conversions ----------------
__global__ void k_cvt_x(const float* __restrict__ x, u16* __restrict__ xb) {
    int i = blockIdx.x * 256 + threadIdx.x;  // element quad
    if ((size_t)i * 4 < (size_t)N_NODES * IN_DIM) {
        float4 v = *reinterpret_cast<const float4*>(x + (size_t)i * 4);
        ushort4 o;
        o.x = f2bf(v.x); o.y = f2bf(v.y); o.z = f2bf(v.z); o.w = f2bf(v.w);
        *reinterpret_cast<ushort4*>(xb + (size_t)i * 4) = o;
    }
}

// enc_w [K=128][N=256] -> encT bf16 [256][128]
__global__ void k_cvt_enc(const float* __restrict__ w, u16* __restrict__ wT) {
    int idx = blockIdx.x * 256 + threadIdx.x;
    if (idx < HDIM * IN_DIM) {
        int n = idx / IN_DIM, k = idx - n * IN_DIM;
        wT[idx] = f2bf(w[(size_t)k * HDIM + n]);
    }
}

// conv_w [L][K=256][N=256] -> convT bf16 [L][256][256] (per-layer transposed)
__global__ void k_cvt_conv(const float* __restrict__ w, u16* __restrict__ wT) {
    int idx = blockIdx.x * 256 + threadIdx.x;
    if (idx < LAYERS * HDIM * HDIM) {
        int l = idx >> 16, i = idx & 65535;
        int n = i >> 8, k = i & 255;
        wT[idx] = f2bf(w[((size_t)l << 16) + (size_t)k * HDIM + n]);
    }
}

// ---------------- bf16 MFMA GEMM: C[M x 256] = A[M x K] @ BT^T ----------------
// LDS tile rows are 64 B (32 bf16); XOR-swizzle s(r) = (r&3)<<4 applied to byte
// offsets within the row, on BOTH the pre-swizzled global source of
// global_load_lds (16B-granular, so chunks stay contiguous) and the ds_read side.
__device__ __forceinline__ bf16x8 load_frag(const u16* __restrict__ lds, int r, int g) {
    const char* rb = (const char*)(lds + r * 32);
    int s = (r & 3) << 4;
    union { struct { unsigned long long lo, hi; } q; bf16x8 v; } u;
    u.q.lo = *(const unsigned long long*)(rb + ((g * 8) ^ s));
    u.q.hi = *(const unsigned long long*)(rb + ((32 + g * 8) ^ s));
    return u.v;
}

template <int K, int MODE>  // MODE 0: write fp32 C (+bias) AND bf16 Cb; MODE 1: bf16 Cb only
__global__ __launch_bounds__(256) void k_gemm_mfma(
    const u16* __restrict__ A, const u16* __restrict__ BT,
    const float* __restrict__ bias, float* __restrict__ C,
    u16* __restrict__ Cb, int M)
{
    __shared__ u16 As[128 * 32];
    __shared__ u16 Bs[128 * 32];
    const int tid = threadIdx.x;
    const int lane = tid & 63;
    const int wv = tid >> 6, wr = wv >> 1, wc = wv & 1;
    const int m0 = blockIdx.x * 128, n0 = blockIdx.y * 128;
    const int g = lane >> 4, lr = lane & 15;

    f32x4 acc[4][4] = {};

    for (int k0 = 0; k0 < K; k0 += 32) {
        __syncthreads();  // previous iter's reads done before overwrite
        #pragma unroll
        for (int j = 0; j < 2; j++) {
            int q = tid + 256 * j;           // chunk id: wave-lane-linear
            int r = q >> 2, c4 = q & 3;
            int boff = (c4 * 16) ^ ((r & 3) << 4);
            int arow = m0 + r; if (arow >= M) arow = M - 1;  // clamp; rows >= M discarded at store
            const char* ga = (const char*)(A + (size_t)arow * K + k0) + boff;
            const char* gb = (const char*)(BT + (size_t)(n0 + r) * K + k0) + boff;
            __builtin_amdgcn_global_load_lds(
                (const __attribute__((address_space(1))) void*)ga,
                (__attribute__((address_space(3))) void*)((char*)As + q * 16), 16, 0, 0);
            __builtin_amdgcn_global_load_lds(
                (const __attribute__((address_space(1))) void*)gb,
                (__attribute__((address_space(3))) void*)((char*)Bs + q * 16), 16, 0, 0);
        }
        __syncthreads();  // drains vmcnt before any wave reads LDS

        bf16x8 af[4], bfr[4];
        #pragma unroll
        for (int mi = 0; mi < 4; mi++) {
            int r = wr * 64 + mi * 16 + lr;
            af[mi] = load_frag(As, r, g);
        }
        #pragma unroll
        for (int ni = 0; ni < 4; ni++) {
            int r = wc * 64 + ni * 16 + lr;
            bfr[ni] = load_frag(Bs, r, g);
        }
        #pragma unroll
        for (int mi = 0; mi < 4; mi++)
            #pragma unroll
            for (int ni = 0; ni < 4; ni++)
                acc[mi][ni] = __builtin_amdgcn_mfma_f32_16x16x32_bf16(
                    af[mi], bfr[ni], acc[mi][ni], 0, 0, 0);
    }

    #pragma unroll
    for (int mi = 0; mi < 4; mi++) {
        #pragma unroll
        for (int rg = 0; rg < 4; rg++) {
            int row = m0 + wr * 64 + mi * 16 + g * 4 + rg;
            if (row >= M) continue;
            #pragma unroll
            for (int ni = 0; ni < 4; ni++) {
                int colg = n0 + wc * 64 + ni * 16 + lr;
                float v = acc[mi][ni][rg];
                if (MODE == 0) {
                    v += bias[colg];
                    C[(size_t)row * HDIM + colg] = v;
                }
                Cb[(size_t)row * HDIM + colg] = f2bf(v);
            }
        }
    }
}

// ---------------- aggregate (bf16 gather) + bias + relu + bn + residual ----------------
// one wave per node; lane owns 4 columns (ushort4 = 8 B loads)
__global__ __launch_bounds__(256) void k_aggregate(
    const u16* __restrict__ mb, const float* __restrict__ dinv,
    const int* __restrict__ rp, const int* __restrict__ col,
    const float* __restrict__ cb, const float* __restrict__ gamma,
    const float* __restrict__ beta, const float* __restrict__ mean,
    const float* __restrict__ var,
    float* __restrict__ h, u16* __restrict__ hb)
{
    const int node = blockIdx.x * 4 + (threadIdx.x >> 6);
    const int lane = threadIdx.x & 63;
    const float di = dinv[node];
    float a0, a1, a2, a3;
    {
        ushort4 v = *reinterpret_cast<const ushort4*>(mb + (size_t)node * HDIM + lane * 4);
        a0 = di * bf2f(v.x); a1 = di * bf2f(v.y);
        a2 = di * bf2f(v.z); a3 = di * bf2f(v.w);
    }
    const int e0 = rp[node], e1 = rp[node + 1];
    for (int t = e0; t < e1; t++) {
        int s = col[t];
        float w = dinv[s];
        ushort4 v = *reinterpret_cast<const ushort4*>(mb + (size_t)s * HDIM + lane * 4);
        a0 += w * bf2f(v.x); a1 += w * bf2f(v.y);
        a2 += w * bf2f(v.z); a3 += w * bf2f(v.w);
    }
    const int c = lane * 4;
    float4 hv = *reinterpret_cast<const float4*>(h + (size_t)node * HDIM + c);
    float o[4] = {a0 * di, a1 * di, a2 * di, a3 * di};
    float hvv[4] = {hv.x, hv.y, hv.z, hv.w};
    float hn[4];
    #pragma unroll
    for (int j = 0; j < 4; j++) {
        float v = o[j] + cb[c + j];
        v = fmaxf(v, 0.f);
        v = (v - mean[c + j]) * rsqrtf(var[c + j] + EPSV) * gamma[c + j] + beta[c + j];
        hn[j] = hvv[j] + v;
    }
    float4 hw; hw.x = hn[0]; hw.y = hn[1]; hw.z = hn[2]; hw.w = hn[3];
    *reinterpret_cast<float4*>(h + (size_t)node * HDIM + c) = hw;
    ushort4 hbv;
    hbv.x = f2bf(hn[0]); hbv.y = f2bf(hn[1]); hbv.z = f2bf(hn[2]); hbv.w = f2bf(hn[3]);
    *reinterpret_cast<ushort4*>(hb + (size_t)node * HDIM + c) = hbv;
}

// ---------------- pooling ----------------
__device__ __forceinline__ int lower_bound_dev(const int* a, int n, int key) {
    int lo = 0, hi = n;
    while (lo < hi) {
        int mid = (lo + hi) >> 1;
        if (a[mid] < key) lo = mid + 1; else hi = mid;
    }
    return lo;
}

__global__ __launch_bounds__(256) void k_pool(const float* __restrict__ h,
                                              const int* __restrict__ batch,
                                              float* __restrict__ gbuf) {
    int g = blockIdx.x;
    int t = threadIdx.x;
    int start = lower_bound_dev(batch, N_NODES, g);
    int end = lower_bound_dev(batch, N_NODES, g + 1);
    float acc = 0.f;
    for (int n = start; n < end; n++) acc += h[(size_t)n * HDIM + t];
    int cnt = end - start;
    float mean = acc / fmaxf((float)cnt, 1.0f);
    gbuf[(size_t)g * 512 + t] = mean;
    gbuf[(size_t)g * 512 + 256 + t] = acc;
}

// ---------------- head ----------------
__global__ __launch_bounds__(256) void k_head(const float* __restrict__ gbuf,
                                              const float* __restrict__ w1,
                                              const float* __restrict__ b1,
                                              const float* __restrict__ w2,
                                              const float* __restrict__ b2,
                                              float* __restrict__ out) {
    int g = blockIdx.x;
    int t = threadIdx.x;
    __shared__ float gs[512];
    __shared__ float red[256];
    gs[t] = gbuf[(size_t)g * 512 + t];
    gs[256 + t] = gbuf[(size_t)g * 512 + 256 + t];
    __syncthreads();
    float acc = b1[t];
    for (int k = 0; k < 512; k++) acc += gs[k] * w1[(size_t)k * HDIM + t];
    acc = fmaxf(acc, 0.f);
    red[t] = acc * w2[t];
    __syncthreads();
    for (int s = 128; s > 0; s >>= 1) {
        if (t < s) red[t] += red[t + s];
        __syncthreads();
    }
    if (t == 0) out[g] = red[0] + b2[0];
}

extern "C" void kernel_launch(void* const* d_in, const int* in_sizes, int n_in,
                              void* d_out, int out_size, void* d_ws, size_t ws_size,
                              hipStream_t stream) {
    const float* x      = (const float*)d_in[0];
    const int*   ei     = (const int*)d_in[1];
    const int*   srcIdx = ei;
    const int*   dstIdx = ei + N_EDGES;
    const int*   batch  = (const int*)d_in[2];
    const float* enc_w  = (const float*)d_in[3];
    const float* enc_b  = (const float*)d_in[4];
    const float* conv_w = (const float*)d_in[5];
    const float* conv_b = (const float*)d_in[6];
    const float* gamma  = (const float*)d_in[7];
    const float* beta   = (const float*)d_in[8];
    const float* bmean  = (const float*)d_in[9];
    const float* bvar   = (const float*)d_in[10];
    const float* w1     = (const float*)d_in[11];
    const float* b1     = (const float*)d_in[12];
    const float* w2     = (const float*)d_in[13];
    const float* b2     = (const float*)d_in[14];
    float* out = (float*)d_out;

    char* ws = (char*)d_ws;
    size_t off = 0;
    auto alloc = [&](size_t bytes) -> void* {
        void* p = ws + off;
        off = (off + bytes + 255) & ~(size_t)255;
        return p;
    };
    int*   cnt   = (int*)alloc((size_t)N_NODES * 4);
    int*   rp    = (int*)alloc((size_t)(N_NODES + 1) * 4);
    int*   col   = (int*)alloc((size_t)N_EDGES * 4);
    float* dinv  = (float*)alloc((size_t)N_NODES * 4);
    float* h     = (float*)alloc((size_t)N_NODES * HDIM * 4);
    u16*   hb    = (u16*)alloc((size_t)N_NODES * HDIM * 2);
    u16*   mb    = (u16*)alloc((size_t)N_NODES * HDIM * 2);  // aliased as xb before conv layers
    u16*   encT  = (u16*)alloc((size_t)HDIM * IN_DIM * 2);
    u16*   convT = (u16*)alloc((size_t)LAYERS * HDIM * HDIM * 2);
    float* gbuf  = (float*)alloc((size_t)N_GRAPHS * 512 * 4);
    u16*   xb    = mb;  // reuse: xb consumed by encoder GEMM before mb is written

    const int nb_nodes = (N_NODES + 255) / 256;
    const int nb_edges = (N_EDGES + 255) / 256;

    // CSR
    k_zero_cnt<<<nb_nodes, 256, 0, stream>>>(cnt);
    k_count<<<nb_edges, 256, 0, stream>>>(dstIdx, cnt);
    k_dinv<<<nb_nodes, 256, 0, stream>>>(cnt, dinv);
    k_scan<<<1, 1024, 0, stream>>>(cnt, rp);
    k_cursor<<<nb_nodes, 256, 0, stream>>>(rp, cnt);
    k_scatter<<<nb_edges, 256, 0, stream>>>(srcIdx, dstIdx, cnt, col);

    // conversions
    k_cvt_x<<<(N_NODES * IN_DIM / 4 + 255) / 256, 256, 0, stream>>>(x, xb);
    k_cvt_enc<<<(HDIM * IN_DIM + 255) / 256, 256, 0, stream>>>(enc_w, encT);
    k_cvt_conv<<<(LAYERS * HDIM * HDIM + 255) / 256, 256, 0, stream>>>(conv_w, convT);

    // encoder: h = x@enc_w + enc_b (fp32 + bf16 copies)
    dim3 gg((N_NODES + 127) / 128, HDIM / 128);
    k_gemm_mfma<IN_DIM, 0><<<gg, 256, 0, stream>>>(xb, encT, enc_b, h, hb, N_NODES);

    // conv layers
    for (int l = 0; l < LAYERS; l++) {
        k_gemm_mfma<HDIM, 1><<<gg, 256, 0, stream>>>(
            hb, convT + (size_t)l * HDIM * HDIM, nullptr, nullptr, mb, N_NODES);
        k_aggregate<<<N_NODES / 4, 256, 0, stream>>>(
            mb, dinv, rp, col,
            conv_b + (size_t)l * HDIM, gamma + (size_t)l * HDIM,
            beta + (size_t)l * HDIM, bmean + (size_t)l * HDIM,
            bvar + (size_t)l * HDIM, h, hb);
    }

    k_pool<<<N_GRAPHS, 256, 0, stream>>>(h, batch, gbuf);
    k_head<<<N_GRAPHS, 256, 0, stream>>>(gbuf, w1, b1, w2, b2, out);
}

// Round 3
// 273.362 us; speedup vs baseline: 2.2221x; 1.4228x over previous
//
#include <hip/hip_runtime.h>

#define N_NODES 20000
#define N_EDGES 320000
#define N_GRAPHS 128
#define IN_DIM 128
#define HDIM 256
#define LAYERS 4
#define EPSV 1e-5f
#define PCH 16
#define SCAN_BLK 1024
#define NSCAN ((N_NODES + SCAN_BLK - 1) / SCAN_BLK)

typedef unsigned short u16;
typedef __attribute__((ext_vector_type(8))) __bf16 bf16x8;
typedef __attribute__((ext_vector_type(4))) float f32x4;

__device__ __forceinline__ u16 f2bf(float f) {
    unsigned int u = __float_as_uint(f);
    u += 0x7FFFu + ((u >> 16) & 1u);
    return (u16)(u >> 16);
}
__device__ __forceinline__ float bf2f(u16 s) {
    return __uint_as_float((unsigned int)s << 16);
}

// ---------------- CSR build ----------------
__global__ void k_zero_cnt(int* cnt) {
    int i = blockIdx.x * 256 + threadIdx.x;
    if (i < N_NODES) cnt[i] = 0;
}

__global__ void k_count(const int* __restrict__ dst, int* __restrict__ cnt) {
    int e = blockIdx.x * 256 + threadIdx.x;
    if (e < N_EDGES) atomicAdd(&cnt[dst[e]], 1);
}

// stage 1: per-1024-block sums of cnt
__global__ __launch_bounds__(SCAN_BLK) void k_scan_sum(const int* __restrict__ cnt,
                                                       int* __restrict__ bsum) {
    __shared__ int wsum[16];
    int tid = threadIdx.x, lane = tid & 63, w = tid >> 6;
    int i = blockIdx.x * SCAN_BLK + tid;
    int v = (i < N_NODES) ? cnt[i] : 0;
    #pragma unroll
    for (int d = 1; d < 64; d <<= 1) v += __shfl_xor(v, d, 64);
    if (lane == 0) wsum[w] = v;
    __syncthreads();
    if (tid == 0) {
        int a = 0;
        for (int k = 0; k < 16; k++) a += wsum[k];
        bsum[blockIdx.x] = a;
    }
}

// stage 2: exclusive scan of NSCAN block sums (tiny)
__global__ void k_scan_off(const int* __restrict__ bsum, int* __restrict__ boff) {
    if (threadIdx.x == 0) {
        int a = 0;
        for (int k = 0; k < NSCAN; k++) { boff[k] = a; a += bsum[k]; }
    }
}

// stage 3: local scan + offset -> rp, cursor, dinv
__global__ __launch_bounds__(SCAN_BLK) void k_scan_write(
    const int* __restrict__ cnt, const int* __restrict__ boff,
    int* __restrict__ rp, int* __restrict__ cursor, float* __restrict__ dinv) {
    __shared__ int wsum[16];
    __shared__ int woff[16];
    int tid = threadIdx.x, lane = tid & 63, w = tid >> 6;
    int i = blockIdx.x * SCAN_BLK + tid;
    int v = (i < N_NODES) ? cnt[i] : 0;
    int x = v;
    #pragma unroll
    for (int d = 1; d < 64; d <<= 1) {
        int t = __shfl_up(x, d, 64);
        if (lane >= d) x += t;
    }
    if (lane == 63) wsum[w] = x;
    __syncthreads();
    if (tid == 0) {
        int a = 0;
        for (int k = 0; k < 16; k++) { woff[k] = a; a += wsum[k]; }
    }
    __syncthreads();
    int incl = x + woff[w] + boff[blockIdx.x];
    if (i < N_NODES) {
        rp[i + 1] = incl;
        cursor[i] = incl - v;
        dinv[i] = rsqrtf((float)v + 1.0f);
    }
    if (blockIdx.x == 0 && tid == 0) rp[0] = 0;
}

__global__ void k_scatter(const int* __restrict__ src, const int* __restrict__ dst,
                          int* __restrict__ cursor, int* __restrict__ col) {
    int e = blockIdx.x * 256 + threadIdx.x;
    if (e < N_EDGES) {
        int d = dst[e];
        int p = atomicAdd(&cursor[d], 1);
        col[p] = src[e];
    }
}

// ---------------- fp32 -> bf16 conversions ----------------
__global__ void k_cvt_x(const float* __restrict__ x, u16* __restrict__ xb) {
    int i = blockIdx.x * 256 + threadIdx.x;
    if ((size_t)i * 4 < (size_t)N_NODES * IN_DIM) {
        float4 v = *reinterpret_cast<const float4*>(x + (size_t)i * 4);
        ushort4 o;
        o.x = f2bf(v.x); o.y = f2bf(v.y); o.z = f2bf(v.z); o.w = f2bf(v.w);
        *reinterpret_cast<ushort4*>(xb + (size_t)i * 4) = o;
    }
}

__global__ void k_cvt_enc(const float* __restrict__ w, u16* __restrict__ wT) {
    int idx = blockIdx.x * 256 + threadIdx.x;
    if (idx < HDIM * IN_DIM) {
        int n = idx / IN_DIM, k = idx - n * IN_DIM;
        wT[idx] = f2bf(w[(size_t)k * HDIM + n]);
    }
}

__global__ void k_cvt_conv(const float* __restrict__ w, u16* __restrict__ wT) {
    int idx = blockIdx.x * 256 + threadIdx.x;
    if (idx < LAYERS * HDIM * HDIM) {
        int l = idx >> 16, i = idx & 65535;
        int n = i >> 8, k = i & 255;
        wT[idx] = f2bf(w[((size_t)l << 16) + (size_t)k * HDIM + n]);
    }
}

// ---------------- bf16 MFMA GEMM ----------------
__device__ __forceinline__ bf16x8 load_frag(const u16* __restrict__ lds, int r, int g) {
    const char* rb = (const char*)(lds + r * 32);
    int s = (r & 3) << 4;
    union { struct { unsigned long long lo, hi; } q; bf16x8 v; } u;
    u.q.lo = *(const unsigned long long*)(rb + ((g * 8) ^ s));
    u.q.hi = *(const unsigned long long*)(rb + ((32 + g * 8) ^ s));
    return u.v;
}

template <int K, int MODE>  // MODE 0: fp32 C (+bias) AND bf16 Cb; MODE 1: bf16 Cb only
__global__ __launch_bounds__(256) void k_gemm_mfma(
    const u16* __restrict__ A, const u16* __restrict__ BT,
    const float* __restrict__ bias, float* __restrict__ C,
    u16* __restrict__ Cb, int M)
{
    __shared__ u16 As[128 * 32];
    __shared__ u16 Bs[128 * 32];
    const int tid = threadIdx.x;
    const int lane = tid & 63;
    const int wv = tid >> 6, wr = wv >> 1, wc = wv & 1;
    const int m0 = blockIdx.x * 128, n0 = blockIdx.y * 128;
    const int g = lane >> 4, lr = lane & 15;

    f32x4 acc[4][4] = {};

    for (int k0 = 0; k0 < K; k0 += 32) {
        __syncthreads();
        #pragma unroll
        for (int j = 0; j < 2; j++) {
            int q = tid + 256 * j;
            int r = q >> 2, c4 = q & 3;
            int boff = (c4 * 16) ^ ((r & 3) << 4);
            int arow = m0 + r; if (arow >= M) arow = M - 1;
            const char* ga = (const char*)(A + (size_t)arow * K + k0) + boff;
            const char* gb = (const char*)(BT + (size_t)(n0 + r) * K + k0) + boff;
            __builtin_amdgcn_global_load_lds(
                (const __attribute__((address_space(1))) void*)ga,
                (__attribute__((address_space(3))) void*)((char*)As + q * 16), 16, 0, 0);
            __builtin_amdgcn_global_load_lds(
                (const __attribute__((address_space(1))) void*)gb,
                (__attribute__((address_space(3))) void*)((char*)Bs + q * 16), 16, 0, 0);
        }
        __syncthreads();

        bf16x8 af[4], bfr[4];
        #pragma unroll
        for (int mi = 0; mi < 4; mi++) af[mi] = load_frag(As, wr * 64 + mi * 16 + lr, g);
        #pragma unroll
        for (int ni = 0; ni < 4; ni++) bfr[ni] = load_frag(Bs, wc * 64 + ni * 16 + lr, g);
        #pragma unroll
        for (int mi = 0; mi < 4; mi++)
            #pragma unroll
            for (int ni = 0; ni < 4; ni++)
                acc[mi][ni] = __builtin_amdgcn_mfma_f32_16x16x32_bf16(
                    af[mi], bfr[ni], acc[mi][ni], 0, 0, 0);
    }

    #pragma unroll
    for (int mi = 0; mi < 4; mi++) {
        #pragma unroll
        for (int rg = 0; rg < 4; rg++) {
            int row = m0 + wr * 64 + mi * 16 + g * 4 + rg;
            if (row >= M) continue;
            #pragma unroll
            for (int ni = 0; ni < 4; ni++) {
                int colg = n0 + wc * 64 + ni * 16 + lr;
                float v = acc[mi][ni][rg];
                if (MODE == 0) {
                    v += bias[colg];
                    C[(size_t)row * HDIM + colg] = v;
                }
                Cb[(size_t)row * HDIM + colg] = f2bf(v);
            }
        }
    }
}

// ---------------- aggregate + bias + relu + bn + residual ----------------
// one wave per node; lanes cooperatively preload 64 edge ids + dinv, broadcast
// via shfl; per-edge row gather 2-way unrolled.
__global__ __launch_bounds__(256) void k_aggregate(
    const u16* __restrict__ mb, const float* __restrict__ dinv,
    const int* __restrict__ rp, const int* __restrict__ col,
    const float* __restrict__ cb, const float* __restrict__ gamma,
    const float* __restrict__ beta, const float* __restrict__ mean,
    const float* __restrict__ var,
    float* __restrict__ h, u16* __restrict__ hb)
{
    const int node = blockIdx.x * 4 + (threadIdx.x >> 6);
    const int lane = threadIdx.x & 63;
    const float di = dinv[node];
    float a0, a1, a2, a3;
    {
        ushort4 v = *reinterpret_cast<const ushort4*>(mb + (size_t)node * HDIM + lane * 4);
        a0 = di * bf2f(v.x); a1 = di * bf2f(v.y);
        a2 = di * bf2f(v.z); a3 = di * bf2f(v.w);
    }
    const int e0 = rp[node], e1 = rp[node + 1];
    for (int base = e0; base < e1; base += 64) {
        int nb = e1 - base; if (nb > 64) nb = 64;
        int s_l = 0; float w_l = 0.f;
        if (lane < nb) { s_l = col[base + lane]; w_l = dinv[s_l]; }
        int t = 0;
        for (; t + 2 <= nb; t += 2) {
            int sA = __shfl(s_l, t, 64);
            int sB = __shfl(s_l, t + 1, 64);
            float wA = __shfl(w_l, t, 64);
            float wB = __shfl(w_l, t + 1, 64);
            ushort4 vA = *reinterpret_cast<const ushort4*>(mb + (size_t)sA * HDIM + lane * 4);
            ushort4 vB = *reinterpret_cast<const ushort4*>(mb + (size_t)sB * HDIM + lane * 4);
            a0 += wA * bf2f(vA.x) + wB * bf2f(vB.x);
            a1 += wA * bf2f(vA.y) + wB * bf2f(vB.y);
            a2 += wA * bf2f(vA.z) + wB * bf2f(vB.z);
            a3 += wA * bf2f(vA.w) + wB * bf2f(vB.w);
        }
        if (t < nb) {
            int sA = __shfl(s_l, t, 64);
            float wA = __shfl(w_l, t, 64);
            ushort4 vA = *reinterpret_cast<const ushort4*>(mb + (size_t)sA * HDIM + lane * 4);
            a0 += wA * bf2f(vA.x); a1 += wA * bf2f(vA.y);
            a2 += wA * bf2f(vA.z); a3 += wA * bf2f(vA.w);
        }
    }
    const int c = lane * 4;
    float4 hv = *reinterpret_cast<const float4*>(h + (size_t)node * HDIM + c);
    float o[4] = {a0 * di, a1 * di, a2 * di, a3 * di};
    float hvv[4] = {hv.x, hv.y, hv.z, hv.w};
    float hn[4];
    #pragma unroll
    for (int j = 0; j < 4; j++) {
        float v = o[j] + cb[c + j];
        v = fmaxf(v, 0.f);
        v = (v - mean[c + j]) * rsqrtf(var[c + j] + EPSV) * gamma[c + j] + beta[c + j];
        hn[j] = hvv[j] + v;
    }
    float4 hw; hw.x = hn[0]; hw.y = hn[1]; hw.z = hn[2]; hw.w = hn[3];
    *reinterpret_cast<float4*>(h + (size_t)node * HDIM + c) = hw;
    ushort4 hbv;
    hbv.x = f2bf(hn[0]); hbv.y = f2bf(hn[1]); hbv.z = f2bf(hn[2]); hbv.w = f2bf(hn[3]);
    *reinterpret_cast<ushort4*>(hb + (size_t)node * HDIM + c) = hbv;
}

// ---------------- pooling: stage 1 partial sums ----------------
__device__ __forceinline__ int lower_bound_dev(const int* a, int n, int key) {
    int lo = 0, hi = n;
    while (lo < hi) {
        int mid = (lo + hi) >> 1;
        if (a[mid] < key) lo = mid + 1; else hi = mid;
    }
    return lo;
}

__global__ __launch_bounds__(256) void k_pool_partial(const float* __restrict__ h,
                                                      const int* __restrict__ batch,
                                                      float* __restrict__ pbuf) {
    int g = blockIdx.x / PCH, c = blockIdx.x % PCH;
    int t = threadIdx.x;
    int start = lower_bound_dev(batch, N_NODES, g);
    int end = lower_bound_dev(batch, N_NODES, g + 1);
    int len = end - start;
    int s0 = start + (int)(((long long)len * c) / PCH);
    int s1 = start + (int)(((long long)len * (c + 1)) / PCH);
    float acc = 0.f;
    for (int n = s0; n < s1; n++) acc += h[(size_t)n * HDIM + t];
    pbuf[(size_t)blockIdx.x * HDIM + t] = acc;
}

// ---------------- head: reduce partials + relu(g@W1+b1)@W2 + b2 ----------------
__global__ __launch_bounds__(256) void k_head(const float* __restrict__ pbuf,
                                              const int* __restrict__ batch,
                                              const float* __restrict__ w1,
                                              const float* __restrict__ b1,
                                              const float* __restrict__ w2,
                                              const float* __restrict__ b2,
                                              float* __restrict__ out) {
    int g = blockIdx.x;
    int t = threadIdx.x;
    __shared__ float gs[512];
    __shared__ float red[256];
    float s = 0.f;
    #pragma unroll
    for (int c = 0; c < PCH; c++) s += pbuf[(size_t)(g * PCH + c) * HDIM + t];
    int start = lower_bound_dev(batch, N_NODES, g);
    int end = lower_bound_dev(batch, N_NODES, g + 1);
    float cntf = fmaxf((float)(end - start), 1.0f);
    gs[t] = s / cntf;       // mean
    gs[256 + t] = s;        // sum
    __syncthreads();
    float acc = b1[t];
    for (int k = 0; k < 512; k++) acc += gs[k] * w1[(size_t)k * HDIM + t];
    acc = fmaxf(acc, 0.f);
    red[t] = acc * w2[t];
    __syncthreads();
    for (int s2 = 128; s2 > 0; s2 >>= 1) {
        if (t < s2) red[t] += red[t + s2];
        __syncthreads();
    }
    if (t == 0) out[g] = red[0] + b2[0];
}

extern "C" void kernel_launch(void* const* d_in, const int* in_sizes, int n_in,
                              void* d_out, int out_size, void* d_ws, size_t ws_size,
                              hipStream_t stream) {
    const float* x      = (const float*)d_in[0];
    const int*   ei     = (const int*)d_in[1];
    const int*   srcIdx = ei;
    const int*   dstIdx = ei + N_EDGES;
    const int*   batch  = (const int*)d_in[2];
    const float* enc_w  = (const float*)d_in[3];
    const float* enc_b  = (const float*)d_in[4];
    const float* conv_w = (const float*)d_in[5];
    const float* conv_b = (const float*)d_in[6];
    const float* gamma  = (const float*)d_in[7];
    const float* beta   = (const float*)d_in[8];
    const float* bmean  = (const float*)d_in[9];
    const float* bvar   = (const float*)d_in[10];
    const float* w1     = (const float*)d_in[11];
    const float* b1     = (const float*)d_in[12];
    const float* w2     = (const float*)d_in[13];
    const float* b2     = (const float*)d_in[14];
    float* out = (float*)d_out;

    char* ws = (char*)d_ws;
    size_t off = 0;
    auto alloc = [&](size_t bytes) -> void* {
        void* p = ws + off;
        off = (off + bytes + 255) & ~(size_t)255;
        return p;
    };
    int*   cnt    = (int*)alloc((size_t)N_NODES * 4);
    int*   cursor = (int*)alloc((size_t)N_NODES * 4);
    int*   rp     = (int*)alloc((size_t)(N_NODES + 1) * 4);
    int*   col    = (int*)alloc((size_t)N_EDGES * 4);
    float* dinv   = (float*)alloc((size_t)N_NODES * 4);
    int*   bsum   = (int*)alloc((size_t)NSCAN * 4);
    int*   boff   = (int*)alloc((size_t)NSCAN * 4);
    float* h      = (float*)alloc((size_t)N_NODES * HDIM * 4);
    u16*   hb     = (u16*)alloc((size_t)N_NODES * HDIM * 2);
    u16*   mb     = (u16*)alloc((size_t)N_NODES * HDIM * 2);
    u16*   encT   = (u16*)alloc((size_t)HDIM * IN_DIM * 2);
    u16*   convT  = (u16*)alloc((size_t)LAYERS * HDIM * HDIM * 2);
    float* pbuf   = (float*)alloc((size_t)N_GRAPHS * PCH * HDIM * 4);
    u16*   xb     = mb;  // xb consumed by encoder GEMM before mb is written

    const int nb_nodes = (N_NODES + 255) / 256;
    const int nb_edges = (N_EDGES + 255) / 256;

    // CSR
    k_zero_cnt<<<nb_nodes, 256, 0, stream>>>(cnt);
    k_count<<<nb_edges, 256, 0, stream>>>(dstIdx, cnt);
    k_scan_sum<<<NSCAN, SCAN_BLK, 0, stream>>>(cnt, bsum);
    k_scan_off<<<1, 64, 0, stream>>>(bsum, boff);
    k_scan_write<<<NSCAN, SCAN_BLK, 0, stream>>>(cnt, boff, rp, cursor, dinv);
    k_scatter<<<nb_edges, 256, 0, stream>>>(srcIdx, dstIdx, cursor, col);

    // conversions
    k_cvt_x<<<(N_NODES * IN_DIM / 4 + 255) / 256, 256, 0, stream>>>(x, xb);
    k_cvt_enc<<<(HDIM * IN_DIM + 255) / 256, 256, 0, stream>>>(enc_w, encT);
    k_cvt_conv<<<(LAYERS * HDIM * HDIM + 255) / 256, 256, 0, stream>>>(conv_w, convT);

    // encoder
    dim3 gg((N_NODES + 127) / 128, HDIM / 128);
    k_gemm_mfma<IN_DIM, 0><<<gg, 256, 0, stream>>>(xb, encT, enc_b, h, hb, N_NODES);

    // conv layers
    for (int l = 0; l < LAYERS; l++) {
        k_gemm_mfma<HDIM, 1><<<gg, 256, 0, stream>>>(
            hb, convT + (size_t)l * HDIM * HDIM, nullptr, nullptr, mb, N_NODES);
        k_aggregate<<<N_NODES / 4, 256, 0, stream>>>(
            mb, dinv, rp, col,
            conv_b + (size_t)l * HDIM, gamma + (size_t)l * HDIM,
            beta + (size_t)l * HDIM, bmean + (size_t)l * HDIM,
            bvar + (size_t)l * HDIM, h, hb);
    }

    // pooling + head
    k_pool_partial<<<N_GRAPHS * PCH, 256, 0, stream>>>(h, batch, pbuf);
    k_head<<<N_GRAPHS, 256, 0, stream>>>(pbuf, batch, w1, b1, w2, b2, out);
}